// Round 2
// baseline (176.667 us; speedup 1.0000x reference)
//
#include <hip/hip_runtime.h>
#include <hip/hip_bf16.h>

// Model_65678639890859: 64-step micro-LSTM (V=6 rows x U=4 units; rows fully
// independent recurrences) producing vels[6], then a memory-bound streaming
// matvec out[p] = (dot(Lsx[p,:], vels), dot(Lsy[p,:], vels)), N=1920*1080.
//
// All tensors are float32 (reference is pure jnp.float32; the "(bf16" in the
// test label is hardcoded template text, not a dtype signal — reading f32 as
// bf16 halves produced the round-1 NaN).
//
// K1: 1 wave, lanes 0..23 = (j,u); cross-lane via DPP quad_perm (rows are
//     aligned lane-quads, ~4cyc vs ~120cyc LDS). vels -> d_ws as f32.
// K2: 2 pixels/lane: 3x float4 loads per matrix, 1x float4 store.

#define V 6
#define U 4
#define SEQLEN 64

__device__ __forceinline__ float sigm(float x) {
    return 1.0f / (1.0f + __expf(-x));
}
__device__ __forceinline__ float tanh_f(float x) {
    // tanh(x) = 1 - 2/(exp(2x)+1); robust at both tails
    float e = __expf(2.0f * x);
    return 1.0f - 2.0f / (e + 1.0f);
}

// DPP quad_perm: xor1 = [1,0,3,2] = 0xB1, xor2 = [2,3,0,1] = 0x4E
template <int CTRL>
__device__ __forceinline__ float qp(float x) {
    return __int_as_float(
        __builtin_amdgcn_mov_dpp(__float_as_int(x), CTRL, 0xF, 0xF, true));
}

__global__ void lstm_vels_kernel(
    const float* __restrict__ vel,
    const float* __restrict__ Wix, const float* __restrict__ Wih, const float* __restrict__ bi,
    const float* __restrict__ Wfx, const float* __restrict__ Wfh, const float* __restrict__ bf_,
    const float* __restrict__ Wox, const float* __restrict__ Woh, const float* __restrict__ bo,
    const float* __restrict__ Wgx, const float* __restrict__ Wgh, const float* __restrict__ bg,
    const float* __restrict__ lin, const float* __restrict__ bl,
    const float* __restrict__ h0,  const float* __restrict__ c0,
    float* __restrict__ vels_out)
{
    const int lane = threadIdx.x;
    if (lane >= V * U) return;          // quads 0..5 stay fully active
    const int j  = lane >> 2;
    const int u  = lane & 3;
    const int r4 = lane * 4;            // row (4j+u) base into W*h weights (24x4)

    // per-lane scalar params
    const float wix = Wix[lane], bii = bi[lane];
    const float wfx = Wfx[lane], bff = bf_[lane];
    const float wox = Wox[lane], boo = bo[lane];
    const float wgx = Wgx[lane], bgg = bg[lane];
    const float li  = lin[lane];
    const float blj = bl[j];

    // dot weights in butterfly arrival order: own(u), u^1, u^2, u^3
    const int k1 = u ^ 1, k2 = u ^ 2, k3 = u ^ 3;
    const float wi0 = Wih[r4 + u],  wi1 = Wih[r4 + k1];
    const float wi2 = Wih[r4 + k2], wi3 = Wih[r4 + k3];
    const float wf0 = Wfh[r4 + u],  wf1 = Wfh[r4 + k1];
    const float wf2 = Wfh[r4 + k2], wf3 = Wfh[r4 + k3];
    const float wo0 = Woh[r4 + u],  wo1 = Woh[r4 + k1];
    const float wo2 = Woh[r4 + k2], wo3 = Woh[r4 + k3];
    const float wg0 = Wgh[r4 + u],  wg1 = Wgh[r4 + k1];
    const float wg2 = Wgh[r4 + k2], wg3 = Wgh[r4 + k3];

    float h = h0[lane];
    float c = c0[lane];
    float x = vel[j];                   // x broadcast per row

    float vels = 0.0f, o = 0.0f;

    // Exact reference semantics:
    //   step0 -> o0; vels = o0; then 63x { vels += o; x = o; step }
    // => vels = 2*o0 + o1 + ... + o62 (o63 computed, discarded)
    for (int i = 0; i < SEQLEN; ++i) {
        if (i > 0) { vels += o; x = o; }

        // gather h[j, u^1], h[j, u^2], h[j, u^3] via quad_perm butterfly
        const float hA = qp<0xB1>(h);
        const float hB = qp<0x4E>(h);
        const float hC = qp<0x4E>(hA);

        float pi = fmaf(wix, x, bii);
        pi = fmaf(wi0, h, pi); pi = fmaf(wi1, hA, pi);
        pi = fmaf(wi2, hB, pi); pi = fmaf(wi3, hC, pi);
        float pf = fmaf(wfx, x, bff);
        pf = fmaf(wf0, h, pf); pf = fmaf(wf1, hA, pf);
        pf = fmaf(wf2, hB, pf); pf = fmaf(wf3, hC, pf);
        float po = fmaf(wox, x, boo);
        po = fmaf(wo0, h, po); po = fmaf(wo1, hA, po);
        po = fmaf(wo2, hB, po); po = fmaf(wo3, hC, po);
        float pg = fmaf(wgx, x, bgg);
        pg = fmaf(wg0, h, pg); pg = fmaf(wg1, hA, pg);
        pg = fmaf(wg2, hB, pg); pg = fmaf(wg3, hC, pg);

        const float it = sigm(pi);
        const float ft = sigm(pf);
        const float ot = sigm(po);
        const float gt = sigm(pg);      // "cbar" is sigmoid in the source

        c = fmaf(ft, c, it * gt);
        h = ot * sigm(c);               // sigmoid, not tanh, as in source

        // out[j] = tanh(sum_u linear[j,u]*h2[j,u] + bl[j]); butterfly sum
        float s = li * h;
        s += qp<0xB1>(s);
        s += qp<0x4E>(s);
        o = tanh_f(s + blj);

        if (i == 0) vels = o;
    }

    if (u == 0) vels_out[j] = vels;
}

__global__ __launch_bounds__(256) void flow_kernel(
    const float* __restrict__ Lsx, const float* __restrict__ Lsy,
    const float* __restrict__ velsp, float* __restrict__ out, int n)
{
    const int t = blockIdx.x * blockDim.x + threadIdx.x;

    float v[6];
#pragma unroll
    for (int k = 0; k < 6; ++k) v[k] = velsp[k];   // uniform, L2-hot

    const int p0 = t * 2;
    if (p0 + 1 < n) {
        // 2 pixels x 6 f32 = 48 B = 3x float4 per matrix; 48t % 16 == 0
        const float4* ax = reinterpret_cast<const float4*>(Lsx + (size_t)p0 * 6);
        const float4* ay = reinterpret_cast<const float4*>(Lsy + (size_t)p0 * 6);
        union { float4 q[3]; float s[12]; } bx, by;
        bx.q[0] = ax[0]; bx.q[1] = ax[1]; bx.q[2] = ax[2];
        by.q[0] = ay[0]; by.q[1] = ay[1]; by.q[2] = ay[2];

        float4 r;
        float fx0 = 0.0f, fy0 = 0.0f, fx1 = 0.0f, fy1 = 0.0f;
#pragma unroll
        for (int k = 0; k < 6; ++k) {
            fx0 = fmaf(bx.s[k],     v[k], fx0);
            fy0 = fmaf(by.s[k],     v[k], fy0);
            fx1 = fmaf(bx.s[6 + k], v[k], fx1);
            fy1 = fmaf(by.s[6 + k], v[k], fy1);
        }
        r.x = fx0; r.y = fy0; r.z = fx1; r.w = fy1;
        reinterpret_cast<float4*>(out)[t] = r;   // out + 4t, 16B-aligned
    } else {
        for (int p = p0; p < n; ++p) {
            float fx = 0.0f, fy = 0.0f;
            for (int k = 0; k < 6; ++k) {
                fx = fmaf(Lsx[(size_t)p * 6 + k], v[k], fx);
                fy = fmaf(Lsy[(size_t)p * 6 + k], v[k], fy);
            }
            out[2 * p]     = fx;
            out[2 * p + 1] = fy;
        }
    }
}

extern "C" void kernel_launch(void* const* d_in, const int* in_sizes, int n_in,
                              void* d_out, int out_size, void* d_ws, size_t ws_size,
                              hipStream_t stream)
{
    const float* vel  = (const float*)d_in[0];
    const float* Lsx  = (const float*)d_in[1];
    const float* Lsy  = (const float*)d_in[2];
    const float* Wix  = (const float*)d_in[3];
    const float* Wih  = (const float*)d_in[4];
    const float* bi   = (const float*)d_in[5];
    const float* Wfx  = (const float*)d_in[6];
    const float* Wfh  = (const float*)d_in[7];
    const float* bf_  = (const float*)d_in[8];
    const float* Wox  = (const float*)d_in[9];
    const float* Woh  = (const float*)d_in[10];
    const float* bo   = (const float*)d_in[11];
    const float* Wgx  = (const float*)d_in[12];
    const float* Wgh  = (const float*)d_in[13];
    const float* bg   = (const float*)d_in[14];
    const float* lin  = (const float*)d_in[15];
    const float* bl   = (const float*)d_in[16];
    const float* h0   = (const float*)d_in[17];
    const float* c0   = (const float*)d_in[18];

    float* vels = (float*)d_ws;
    const int n = in_sizes[1] / V;

    lstm_vels_kernel<<<1, 64, 0, stream>>>(vel, Wix, Wih, bi, Wfx, Wfh, bf_,
                                           Wox, Woh, bo, Wgx, Wgh, bg,
                                           lin, bl, h0, c0, vels);

    const int nt = (n + 1) / 2;
    flow_kernel<<<(nt + 255) / 256, 256, 0, stream>>>(Lsx, Lsy, vels,
                                                      (float*)d_out, n);
}

// Round 3
// 173.933 us; speedup vs baseline: 1.0157x; 1.0157x over previous
//
#include <hip/hip_runtime.h>
#include <hip/hip_bf16.h>

// Model_65678639890859 — fused single kernel.
//
// Phase 1 (per block, wave 0, lanes 0..23): the 64-step micro-LSTM
// (V=6 rows x U=4 units; rows are independent recurrences; lane=(j,u),
// cross-lane via DPP quad_perm since rows are aligned lane-quads).
// Redundant per block (~45 KFLOP) -> vels[6] in LDS. Paying ~4us of
// dependent-chain latency concurrently in all resident blocks beats the
// serialized 2-kernel structure (1-block dispatch + stream drain).
//
// Phase 2 (all 256 threads, grid-stride): memory-bound streaming matvec
// out[p] = (dot(Lsx[p,:], vels), dot(Lsy[p,:], vels)), N=1920*1080.
// 2 pixels/thread/iter = 3x float4 per matrix (48B, 16B-aligned), one
// float4 store. Grid = 1024 blocks (4/CU, 16 waves/CU, single residency
// round => LSTM latency paid once).
//
// All tensors float32 (reference is pure jnp.float32).

#define V 6
#define U 4
#define SEQLEN 64

__device__ __forceinline__ float sigm(float x) {
    return 1.0f / (1.0f + __expf(-x));
}
__device__ __forceinline__ float tanh_f(float x) {
    // tanh(x) = 1 - 2/(exp(2x)+1); robust at both tails
    float e = __expf(2.0f * x);
    return 1.0f - 2.0f / (e + 1.0f);
}

// DPP quad_perm: xor1 = [1,0,3,2] = 0xB1, xor2 = [2,3,0,1] = 0x4E
template <int CTRL>
__device__ __forceinline__ float qp(float x) {
    return __int_as_float(
        __builtin_amdgcn_mov_dpp(__float_as_int(x), CTRL, 0xF, 0xF, true));
}

__global__ __launch_bounds__(256, 4) void fused_lstm_flow_kernel(
    const float* __restrict__ vel,
    const float* __restrict__ Wix, const float* __restrict__ Wih, const float* __restrict__ bi,
    const float* __restrict__ Wfx, const float* __restrict__ Wfh, const float* __restrict__ bf_,
    const float* __restrict__ Wox, const float* __restrict__ Woh, const float* __restrict__ bo,
    const float* __restrict__ Wgx, const float* __restrict__ Wgh, const float* __restrict__ bg,
    const float* __restrict__ lin, const float* __restrict__ bl,
    const float* __restrict__ h0,  const float* __restrict__ c0,
    const float* __restrict__ Lsx, const float* __restrict__ Lsy,
    float* __restrict__ out, int n)
{
    __shared__ float vels_s[8];

    // ---- Phase 1: LSTM on wave 0, lanes 0..23 ----
    if (threadIdx.x < 24) {
        const int lane = threadIdx.x;
        const int j  = lane >> 2;
        const int u  = lane & 3;
        const int r4 = lane * 4;        // row (4j+u) base into W*h weights (24x4)

        const float wix = Wix[lane], bii = bi[lane];
        const float wfx = Wfx[lane], bff = bf_[lane];
        const float wox = Wox[lane], boo = bo[lane];
        const float wgx = Wgx[lane], bgg = bg[lane];
        const float li  = lin[lane];
        const float blj = bl[j];

        // dot weights in butterfly arrival order: own(u), u^1, u^2, u^3
        const int k1 = u ^ 1, k2 = u ^ 2, k3 = u ^ 3;
        const float wi0 = Wih[r4 + u],  wi1 = Wih[r4 + k1];
        const float wi2 = Wih[r4 + k2], wi3 = Wih[r4 + k3];
        const float wf0 = Wfh[r4 + u],  wf1 = Wfh[r4 + k1];
        const float wf2 = Wfh[r4 + k2], wf3 = Wfh[r4 + k3];
        const float wo0 = Woh[r4 + u],  wo1 = Woh[r4 + k1];
        const float wo2 = Woh[r4 + k2], wo3 = Woh[r4 + k3];
        const float wg0 = Wgh[r4 + u],  wg1 = Wgh[r4 + k1];
        const float wg2 = Wgh[r4 + k2], wg3 = Wgh[r4 + k3];

        float h = h0[lane];
        float c = c0[lane];
        float x = vel[j];               // x broadcast per row

        float vels = 0.0f, o = 0.0f;

        // Exact reference semantics:
        //   step0 -> o0; vels = o0; then 63x { vels += o; x = o; step }
        // => vels = 2*o0 + o1 + ... + o62 (o63 computed, discarded)
        for (int i = 0; i < SEQLEN; ++i) {
            if (i > 0) { vels += o; x = o; }

            const float hA = qp<0xB1>(h);
            const float hB = qp<0x4E>(h);
            const float hC = qp<0x4E>(hA);

            float pi = fmaf(wix, x, bii);
            pi = fmaf(wi0, h, pi); pi = fmaf(wi1, hA, pi);
            pi = fmaf(wi2, hB, pi); pi = fmaf(wi3, hC, pi);
            float pf = fmaf(wfx, x, bff);
            pf = fmaf(wf0, h, pf); pf = fmaf(wf1, hA, pf);
            pf = fmaf(wf2, hB, pf); pf = fmaf(wf3, hC, pf);
            float po = fmaf(wox, x, boo);
            po = fmaf(wo0, h, po); po = fmaf(wo1, hA, po);
            po = fmaf(wo2, hB, po); po = fmaf(wo3, hC, po);
            float pg = fmaf(wgx, x, bgg);
            pg = fmaf(wg0, h, pg); pg = fmaf(wg1, hA, pg);
            pg = fmaf(wg2, hB, pg); pg = fmaf(wg3, hC, pg);

            const float it = sigm(pi);
            const float ft = sigm(pf);
            const float ot = sigm(po);
            const float gt = sigm(pg);  // "cbar" is sigmoid in the source

            c = fmaf(ft, c, it * gt);
            h = ot * sigm(c);           // sigmoid, not tanh, as in source

            float s = li * h;
            s += qp<0xB1>(s);
            s += qp<0x4E>(s);
            o = tanh_f(s + blj);

            if (i == 0) vels = o;
        }

        if (u == 0) vels_s[j] = vels;
    }

    __syncthreads();

    // ---- Phase 2: streaming matvec, grid-stride over pixel pairs ----
    const float v0 = vels_s[0], v1 = vels_s[1], v2 = vels_s[2];
    const float v3 = vels_s[3], v4 = vels_s[4], v5 = vels_s[5];

    const int nt = n >> 1;  // pixel pairs (N even)
    const int stride = gridDim.x * blockDim.x;

    for (int tp = blockIdx.x * blockDim.x + threadIdx.x; tp < nt; tp += stride) {
        // 2 pixels x 6 f32 = 48 B = 3x float4 per matrix; 48*tp % 16 == 0
        const float4* ax = reinterpret_cast<const float4*>(Lsx + (size_t)tp * 12);
        const float4* ay = reinterpret_cast<const float4*>(Lsy + (size_t)tp * 12);
        union { float4 q[3]; float s[12]; } bx, by;
        bx.q[0] = ax[0]; bx.q[1] = ax[1]; bx.q[2] = ax[2];
        by.q[0] = ay[0]; by.q[1] = ay[1]; by.q[2] = ay[2];

        float fx0 = bx.s[0] * v0, fy0 = by.s[0] * v0;
        float fx1 = bx.s[6] * v0, fy1 = by.s[6] * v0;
        fx0 = fmaf(bx.s[1],  v1, fx0); fy0 = fmaf(by.s[1],  v1, fy0);
        fx1 = fmaf(bx.s[7],  v1, fx1); fy1 = fmaf(by.s[7],  v1, fy1);
        fx0 = fmaf(bx.s[2],  v2, fx0); fy0 = fmaf(by.s[2],  v2, fy0);
        fx1 = fmaf(bx.s[8],  v2, fx1); fy1 = fmaf(by.s[8],  v2, fy1);
        fx0 = fmaf(bx.s[3],  v3, fx0); fy0 = fmaf(by.s[3],  v3, fy0);
        fx1 = fmaf(bx.s[9],  v3, fx1); fy1 = fmaf(by.s[9],  v3, fy1);
        fx0 = fmaf(bx.s[4],  v4, fx0); fy0 = fmaf(by.s[4],  v4, fy0);
        fx1 = fmaf(bx.s[10], v4, fx1); fy1 = fmaf(by.s[10], v4, fy1);
        fx0 = fmaf(bx.s[5],  v5, fx0); fy0 = fmaf(by.s[5],  v5, fy0);
        fx1 = fmaf(bx.s[11], v5, fx1); fy1 = fmaf(by.s[11], v5, fy1);

        float4 r;
        r.x = fx0; r.y = fy0; r.z = fx1; r.w = fy1;
        reinterpret_cast<float4*>(out)[tp] = r;
    }

    // Tail pixel if n is odd (not hit for 1920*1080, kept for generality)
    if ((n & 1) && blockIdx.x == 0 && threadIdx.x == 0) {
        const int p = n - 1;
        float fx = 0.0f, fy = 0.0f;
        const float vv[6] = {v0, v1, v2, v3, v4, v5};
        for (int k = 0; k < 6; ++k) {
            fx = fmaf(Lsx[(size_t)p * 6 + k], vv[k], fx);
            fy = fmaf(Lsy[(size_t)p * 6 + k], vv[k], fy);
        }
        out[2 * p]     = fx;
        out[2 * p + 1] = fy;
    }
}

extern "C" void kernel_launch(void* const* d_in, const int* in_sizes, int n_in,
                              void* d_out, int out_size, void* d_ws, size_t ws_size,
                              hipStream_t stream)
{
    const float* vel  = (const float*)d_in[0];
    const float* Lsx  = (const float*)d_in[1];
    const float* Lsy  = (const float*)d_in[2];
    const float* Wix  = (const float*)d_in[3];
    const float* Wih  = (const float*)d_in[4];
    const float* bi   = (const float*)d_in[5];
    const float* Wfx  = (const float*)d_in[6];
    const float* Wfh  = (const float*)d_in[7];
    const float* bf_  = (const float*)d_in[8];
    const float* Wox  = (const float*)d_in[9];
    const float* Woh  = (const float*)d_in[10];
    const float* bo   = (const float*)d_in[11];
    const float* Wgx  = (const float*)d_in[12];
    const float* Wgh  = (const float*)d_in[13];
    const float* bg   = (const float*)d_in[14];
    const float* lin  = (const float*)d_in[15];
    const float* bl   = (const float*)d_in[16];
    const float* h0   = (const float*)d_in[17];
    const float* c0   = (const float*)d_in[18];

    const int n = in_sizes[1] / V;

    // 4 blocks/CU x 256 CUs = 1024 blocks: one residency round, LSTM
    // latency paid exactly once, concurrently, in every block.
    const int nblocks = 1024;
    fused_lstm_flow_kernel<<<nblocks, 256, 0, stream>>>(
        vel, Wix, Wih, bi, Wfx, Wfh, bf_, Wox, Woh, bo, Wgx, Wgh, bg,
        lin, bl, h0, c0, Lsx, Lsy, (float*)d_out, n);
}

// Round 4
// 167.125 us; speedup vs baseline: 1.0571x; 1.0407x over previous
//
#include <hip/hip_runtime.h>
#include <hip/hip_bf16.h>

// Model_65678639890859 — fused single kernel, round 4.
//
// Phase 1 (per block, wave 0, lanes 0..23): 64-step micro-LSTM (V=6 rows x
// U=4 units; rows independent; lane=(j,u); cross-lane via DPP quad_perm).
// Round-3 lesson: 1.0f/x compiled to IEEE div sequences (~6 per step, ~50-80
// dependent cyc each) => ~20-30us of serialized latency. Now sigm/tanh use
// v_rcp_f32 + v_exp_f32 directly (~120 cyc/step => ~3us total).
//
// Phase 2: memory-bound streaming matvec out[p]=(Lsx[p,:].vels, Lsy[p,:].vels),
// N=1920*1080, 2 pixels/thread/iter (3x float4 per matrix), float4 store.
// First iteration's loads are issued BEFORE the LSTM branch (they fly during
// phase 1); main loop register-double-buffers (load i+1, compute i).
//
// All tensors float32. Grid = 1024 blocks (4/CU, one residency round).

#define V 6
#define U 4
#define SEQLEN 64

__device__ __forceinline__ float frcp(float x)  { return __builtin_amdgcn_rcpf(x); }
__device__ __forceinline__ float fexp2(float x) { return __builtin_amdgcn_exp2f(x); }

// sigmoid(x) = 1/(1+exp(-x)) = rcp(1 + exp2(-x*log2e))
__device__ __forceinline__ float sigm(float x) {
    return frcp(1.0f + fexp2(-1.442695041f * x));
}
// tanh(x) = 1 - 2/(exp(2x)+1) = 1 - 2*rcp(exp2(2x*log2e)+1); tail-robust:
// exp2 overflow -> inf -> rcp=0 -> 1; underflow -> 0 -> rcp(1)=1 -> -1.
__device__ __forceinline__ float tanh_f(float x) {
    return 1.0f - 2.0f * frcp(fexp2(2.885390082f * x) + 1.0f);
}

// DPP quad_perm: xor1 = [1,0,3,2] = 0xB1, xor2 = [2,3,0,1] = 0x4E
template <int CTRL>
__device__ __forceinline__ float qp(float x) {
    return __int_as_float(
        __builtin_amdgcn_mov_dpp(__float_as_int(x), CTRL, 0xF, 0xF, true));
}

typedef union { float4 q[3]; float s[12]; } P12;

__global__ __launch_bounds__(256, 4) void fused_lstm_flow_kernel(
    const float* __restrict__ vel,
    const float* __restrict__ Wix, const float* __restrict__ Wih, const float* __restrict__ bi,
    const float* __restrict__ Wfx, const float* __restrict__ Wfh, const float* __restrict__ bf_,
    const float* __restrict__ Wox, const float* __restrict__ Woh, const float* __restrict__ bo,
    const float* __restrict__ Wgx, const float* __restrict__ Wgh, const float* __restrict__ bg,
    const float* __restrict__ lin, const float* __restrict__ bl,
    const float* __restrict__ h0,  const float* __restrict__ c0,
    const float* __restrict__ Lsx, const float* __restrict__ Lsy,
    float* __restrict__ out, int n)
{
    __shared__ float vels_s[8];

    const int tid    = threadIdx.x;
    const int nt     = n >> 1;                 // pixel pairs
    const int stride = gridDim.x * blockDim.x;
    int tp = blockIdx.x * blockDim.x + tid;
    const bool have = tp < nt;

    // ---- Prefetch first phase-2 iteration (flies during the LSTM) ----
    P12 bx, by;
    if (have) {
        const float4* ax = reinterpret_cast<const float4*>(Lsx + (size_t)tp * 12);
        const float4* ay = reinterpret_cast<const float4*>(Lsy + (size_t)tp * 12);
        bx.q[0] = ax[0]; bx.q[1] = ax[1]; bx.q[2] = ax[2];
        by.q[0] = ay[0]; by.q[1] = ay[1]; by.q[2] = ay[2];
    }

    // ---- Phase 1: LSTM on wave 0, lanes 0..23 ----
    if (tid < 24) {
        const int lane = tid;
        const int j  = lane >> 2;
        const int u  = lane & 3;
        const int r4 = lane * 4;        // row (4j+u) base into W*h weights (24x4)

        const float wix = Wix[lane], bii = bi[lane];
        const float wfx = Wfx[lane], bff = bf_[lane];
        const float wox = Wox[lane], boo = bo[lane];
        const float wgx = Wgx[lane], bgg = bg[lane];
        const float li  = lin[lane];
        const float blj = bl[j];

        // dot weights in butterfly arrival order: own(u), u^1, u^2, u^3
        const int k1 = u ^ 1, k2 = u ^ 2, k3 = u ^ 3;
        const float wi0 = Wih[r4 + u],  wi1 = Wih[r4 + k1];
        const float wi2 = Wih[r4 + k2], wi3 = Wih[r4 + k3];
        const float wf0 = Wfh[r4 + u],  wf1 = Wfh[r4 + k1];
        const float wf2 = Wfh[r4 + k2], wf3 = Wfh[r4 + k3];
        const float wo0 = Woh[r4 + u],  wo1 = Woh[r4 + k1];
        const float wo2 = Woh[r4 + k2], wo3 = Woh[r4 + k3];
        const float wg0 = Wgh[r4 + u],  wg1 = Wgh[r4 + k1];
        const float wg2 = Wgh[r4 + k2], wg3 = Wgh[r4 + k3];

        float h = h0[lane];
        float c = c0[lane];
        float x = vel[j];               // x broadcast per row

        float vels = 0.0f, o = 0.0f;

        // Exact reference semantics:
        //   step0 -> o0; vels = o0; then 63x { vels += o; x = o; step }
        // => vels = 2*o0 + o1 + ... + o62 (o63 computed, discarded)
        for (int i = 0; i < SEQLEN; ++i) {
            if (i > 0) { vels += o; x = o; }

            const float hA = qp<0xB1>(h);
            const float hB = qp<0x4E>(h);
            const float hC = qp<0x4E>(hA);

            float pi = fmaf(wix, x, bii);
            pi = fmaf(wi0, h, pi); pi = fmaf(wi1, hA, pi);
            pi = fmaf(wi2, hB, pi); pi = fmaf(wi3, hC, pi);
            float pf = fmaf(wfx, x, bff);
            pf = fmaf(wf0, h, pf); pf = fmaf(wf1, hA, pf);
            pf = fmaf(wf2, hB, pf); pf = fmaf(wf3, hC, pf);
            float po = fmaf(wox, x, boo);
            po = fmaf(wo0, h, po); po = fmaf(wo1, hA, po);
            po = fmaf(wo2, hB, po); po = fmaf(wo3, hC, po);
            float pg = fmaf(wgx, x, bgg);
            pg = fmaf(wg0, h, pg); pg = fmaf(wg1, hA, pg);
            pg = fmaf(wg2, hB, pg); pg = fmaf(wg3, hC, pg);

            const float it = sigm(pi);
            const float ft = sigm(pf);
            const float ot = sigm(po);
            const float gt = sigm(pg);  // "cbar" is sigmoid in the source

            c = fmaf(ft, c, it * gt);
            h = ot * sigm(c);           // sigmoid, not tanh, as in source

            float s = li * h;
            s += qp<0xB1>(s);
            s += qp<0x4E>(s);
            o = tanh_f(s + blj);

            if (i == 0) vels = o;
        }

        if (u == 0) vels_s[j] = vels;
    }

    __syncthreads();

    const float v0 = vels_s[0], v1 = vels_s[1], v2 = vels_s[2];
    const float v3 = vels_s[3], v4 = vels_s[4], v5 = vels_s[5];

    // ---- Phase 2: pipelined grid-stride over pixel pairs ----
    if (have) {
        for (;;) {
            const int tn = tp + stride;
            const bool more = tn < nt;

            P12 nx, ny;
            if (more) {
                const float4* ax = reinterpret_cast<const float4*>(Lsx + (size_t)tn * 12);
                const float4* ay = reinterpret_cast<const float4*>(Lsy + (size_t)tn * 12);
                nx.q[0] = ax[0]; nx.q[1] = ax[1]; nx.q[2] = ax[2];
                ny.q[0] = ay[0]; ny.q[1] = ay[1]; ny.q[2] = ay[2];
            }

            float fx0 = bx.s[0] * v0, fy0 = by.s[0] * v0;
            float fx1 = bx.s[6] * v0, fy1 = by.s[6] * v0;
            fx0 = fmaf(bx.s[1],  v1, fx0); fy0 = fmaf(by.s[1],  v1, fy0);
            fx1 = fmaf(bx.s[7],  v1, fx1); fy1 = fmaf(by.s[7],  v1, fy1);
            fx0 = fmaf(bx.s[2],  v2, fx0); fy0 = fmaf(by.s[2],  v2, fy0);
            fx1 = fmaf(bx.s[8],  v2, fx1); fy1 = fmaf(by.s[8],  v2, fy1);
            fx0 = fmaf(bx.s[3],  v3, fx0); fy0 = fmaf(by.s[3],  v3, fy0);
            fx1 = fmaf(bx.s[9],  v3, fx1); fy1 = fmaf(by.s[9],  v3, fy1);
            fx0 = fmaf(bx.s[4],  v4, fx0); fy0 = fmaf(by.s[4],  v4, fy0);
            fx1 = fmaf(bx.s[10], v4, fx1); fy1 = fmaf(by.s[10], v4, fy1);
            fx0 = fmaf(bx.s[5],  v5, fx0); fy0 = fmaf(by.s[5],  v5, fy0);
            fx1 = fmaf(bx.s[11], v5, fx1); fy1 = fmaf(by.s[11], v5, fy1);

            float4 r;
            r.x = fx0; r.y = fy0; r.z = fx1; r.w = fy1;
            reinterpret_cast<float4*>(out)[tp] = r;

            if (!more) break;
            bx = nx; by = ny; tp = tn;
        }
    }

    // Tail pixel if n is odd (not hit for 1920*1080, kept for generality)
    if ((n & 1) && blockIdx.x == 0 && tid == 0) {
        const int p = n - 1;
        float fx = 0.0f, fy = 0.0f;
        const float vv[6] = {v0, v1, v2, v3, v4, v5};
        for (int k = 0; k < 6; ++k) {
            fx = fmaf(Lsx[(size_t)p * 6 + k], vv[k], fx);
            fy = fmaf(Lsy[(size_t)p * 6 + k], vv[k], fy);
        }
        out[2 * p]     = fx;
        out[2 * p + 1] = fy;
    }
}

extern "C" void kernel_launch(void* const* d_in, const int* in_sizes, int n_in,
                              void* d_out, int out_size, void* d_ws, size_t ws_size,
                              hipStream_t stream)
{
    const float* vel  = (const float*)d_in[0];
    const float* Lsx  = (const float*)d_in[1];
    const float* Lsy  = (const float*)d_in[2];
    const float* Wix  = (const float*)d_in[3];
    const float* Wih  = (const float*)d_in[4];
    const float* bi   = (const float*)d_in[5];
    const float* Wfx  = (const float*)d_in[6];
    const float* Wfh  = (const float*)d_in[7];
    const float* bf_  = (const float*)d_in[8];
    const float* Wox  = (const float*)d_in[9];
    const float* Woh  = (const float*)d_in[10];
    const float* bo   = (const float*)d_in[11];
    const float* Wgx  = (const float*)d_in[12];
    const float* Wgh  = (const float*)d_in[13];
    const float* bg   = (const float*)d_in[14];
    const float* lin  = (const float*)d_in[15];
    const float* bl   = (const float*)d_in[16];
    const float* h0   = (const float*)d_in[17];
    const float* c0   = (const float*)d_in[18];

    const int n = in_sizes[1] / V;

    // 4 blocks/CU x 256 CUs = 1024 blocks: one residency round, LSTM
    // latency paid exactly once, concurrently, in every block.
    const int nblocks = 1024;
    fused_lstm_flow_kernel<<<nblocks, 256, 0, stream>>>(
        vel, Wix, Wih, bi, Wfx, Wfh, bf_, Wox, Woh, bo, Wgx, Wgh, bg,
        lin, bl, h0, c0, Lsx, Lsy, (float*)d_out, n);
}